// Round 6
// baseline (447.272 us; speedup 1.0000x reference)
//
#include <hip/hip_runtime.h>
#include <math.h>

// ---- geometry constants (match reference) ----
#define NA   24
#define NU   128
#define NV   64
#define NW   128   // volume W (x)
#define NH   128   // volume H (y)
#define ND   64    // volume D (z)
#define NS   128   // samples per ray
#define F_STEP 1.5625f            // 2*HS/S = 200/128
#define F_DL  (200.0f / 127.0f)   // linspace(156,356,128) spacing
#define F_L0  156.0f
#define INV_DL (127.0f / 200.0f)

#define NRAYS (NA * NV * NU)      // 196608
#define VOX   (NW * NH * ND)      // 1048576
#define NSEG  4

// padded volume: planes {guard, padz(-1), z0..z63, padz(64), guard} x 130 x 130
#define PPX  130
#define PPY  130
#define PPZ  68
#define PPLANE (PPX * PPY)        // 16900
#define PVN  (PPZ * PPLANE)       // 1,149,200
#define CBASE (2 * PPLANE + PPX + 1)   // voxel(0,0,0) linear offset

typedef float v2f __attribute__((ext_vector_type(2)));

// cos/sin(k*15 deg)
__device__ __constant__ float CSA[NA] = {
    1.0f,  0.96592582628906829f,  0.86602540378443865f,  0.70710678118654752f,
    0.5f,  0.25881904510252076f,  0.0f,                 -0.25881904510252076f,
   -0.5f, -0.70710678118654752f, -0.86602540378443865f, -0.96592582628906829f,
   -1.0f, -0.96592582628906829f, -0.86602540378443865f, -0.70710678118654752f,
   -0.5f, -0.25881904510252076f,  0.0f,                  0.25881904510252076f,
    0.5f,  0.70710678118654752f,  0.86602540378443865f,  0.96592582628906829f
};
__device__ __constant__ float SNA[NA] = {
    0.0f,  0.25881904510252076f,  0.5f,                  0.70710678118654752f,
    0.86602540378443865f,  0.96592582628906829f,  1.0f,  0.96592582628906829f,
    0.86602540378443865f,  0.70710678118654752f,  0.5f,  0.25881904510252076f,
    0.0f, -0.25881904510252076f, -0.5f,                 -0.70710678118654752f,
   -0.86602540378443865f, -0.96592582628906829f, -1.0f, -0.96592582628906829f,
   -0.86602540378443865f, -0.70710678118654752f, -0.5f, -0.25881904510252076f
};

// ---------------- volume padding: zero borders, copy interior ----------------
__global__ __launch_bounds__(256) void pad_kernel(const float* __restrict__ vol,
                                                  float* __restrict__ padv) {
    int i = blockIdx.x * 256 + threadIdx.x;
    if (i >= PVN) return;
    int x = i % PPX;
    int t = i / PPX;
    int y = t % PPY;
    int z = t / PPY;
    float val = 0.0f;
    if (z >= 2 && z <= 65 && y >= 1 && y <= 128 && x >= 1 && x <= 128)
        val = vol[(((z - 2) << 7) + (y - 1) << 7) + (x - 1)];
    padv[i] = val;
}

// Per-ray geometry for FP.
__device__ __forceinline__ void ray_setup(int a, int v, int u,
                                          float& sx, float& sy,
                                          float& dx, float& dy, float& dz) {
    float ang = (float)((double)a * (15.0 * M_PI / 180.0));
    float c = cosf(ang), s = sinf(ang);
    float uu = (float)u - 63.5f;
    float vv = (float)v - 31.5f;
    float ux = 512.0f * c - uu * s;
    float uy = 512.0f * s + uu * c;
    float uz = vv;
    float invn = 1.0f / sqrtf(ux * ux + uy * uy + uz * uz);
    dx = ux * invn; dy = uy * invn; dz = uz * invn;
    sx = -256.0f * c; sy = -256.0f * s;
}

// ---------------- forward projection, 4 ell-segments, padded-volume gather ----------------
__global__ __launch_bounds__(256) void fp_seg_kernel(const float* __restrict__ padv,
                                                     float* __restrict__ part) {
    int r = blockIdx.x * blockDim.x + threadIdx.x;
    int seg = blockIdx.y;
    int u = r & (NU - 1);
    int v = (r >> 7) & (NV - 1);
    int a = r >> 13;

    float sx, sy, dx, dy, dz;
    ray_setup(a, v, u, sx, sy, dx, dy, dz);

    // exact-support window (voxel weights are zero outside +-64.5 / +-32.5)
    float rx = 1.0f / dx, ry = 1.0f / dy, rz = 1.0f / dz;
    float ex0 = (-64.51f - sx) * rx, ex1 = (64.51f - sx) * rx;
    float ey0 = (-64.51f - sy) * ry, ey1 = (64.51f - sy) * ry;
    float ez0 = (-32.51f) * rz,      ez1 = (32.51f) * rz;
    float llo = fmaxf(fmaxf(fminf(ex0, ex1), fminf(ey0, ey1)), fminf(ez0, ez1));
    float lhi = fminf(fminf(fmaxf(ex0, ex1), fmaxf(ey0, ey1)), fmaxf(ez0, ez1));
    int i_lo = max(seg * 32,      (int)ceilf((llo - F_L0) * INV_DL));
    int i_hi = min(seg * 32 + 31, (int)floorf((lhi - F_L0) * INV_DL));

    float acc = 0.0f;
    for (int i = i_lo; i <= i_hi; ++i) {
        float ell = fmaf((float)i, F_DL, F_L0);
        float cx = fmaf(ell, dx, sx) + 63.5f;   // voxel-index space
        float cy = fmaf(ell, dy, sy) + 63.5f;
        float cz = ell * dz + 31.5f;
        float fx = floorf(cx), fy = floorf(cy), fz = floorf(cz);
        int ix = (int)fx, iy = (int)fy, iz = (int)fz;
        float wx1 = cx - fx, wy1 = cy - fy, wz1 = cz - fz;
        int base = iz * PPLANE + iy * PPX + ix + CBASE;
        const float* q0 = padv + base;
        const float* q1 = q0 + PPLANE;
        float v000 = q0[0],   v001 = q0[1];
        float v010 = q0[PPX], v011 = q0[PPX + 1];
        float v100 = q1[0],   v101 = q1[1];
        float v110 = q1[PPX], v111 = q1[PPX + 1];
        float c00 = fmaf(wx1, v001 - v000, v000);
        float c01 = fmaf(wx1, v011 - v010, v010);
        float c10 = fmaf(wx1, v101 - v100, v100);
        float c11 = fmaf(wx1, v111 - v110, v110);
        float c0  = fmaf(wy1, c01 - c00, c00);
        float c1  = fmaf(wy1, c11 - c10, c10);
        acc += fmaf(wz1, c1 - c0, c0);
    }
    part[seg * NRAYS + r] = acc;
}

// ------- residual + cw + Ram-Lak; writes TRANSPOSED resT[a][u][v] -------
__global__ __launch_bounds__(NU) void ramp_kernel(const float* __restrict__ part,
                                                  const float* __restrict__ p,
                                                  float* __restrict__ resT) {
    __shared__ float row[NU];
    int rowid = blockIdx.x;          // a*NV + v
    int u = threadIdx.x;
    int e = rowid * NU + u;
    int a = rowid >> 6;
    int v = rowid & (NV - 1);
    float sino = (part[e] + part[NRAYS + e] + part[2 * NRAYS + e] + part[3 * NRAYS + e]) * F_STEP;
    double du = (double)u - 64.0;
    double dv = (double)v - 32.0;
    float cw = (float)(512.0 / sqrt(262144.0 + dv * dv + du * du));
    row[u] = (sino - p[e]) * cw;
    __syncthreads();
    float acc = 0.125f * row[u];
#pragma unroll
    for (int d = 1; d <= 63; d += 2) {
        float f = (float)(-0.5 / (M_PI * M_PI * (double)(d * d)));
        float lo = (u - d >= 0) ? row[u - d] : 0.0f;
        float hi = (u + d < NU) ? row[u + d] : 0.0f;
        acc += f * (lo + hi);
    }
    resT[(a << 13) + (u << 6) + v] = acc;   // [a][u][v]
}

// ---------------- back projection: R4 kernel + scrambled block order ----------------
// R21. Evidence synthesis (R0-R5):
//  * VALU issue floor = 160us/SIMD: static count (~12K VALU/wave x 2cy x 16
//    waves/SIMD) == measured VALUBusy x dur (161us) in EVERY round. Honest.
//  * Wall = 2.1x that floor, INVARIANT under: memory-path surgery (R5: full
//    LDS staging, vmcnt(0)/pair -> null), setup prefetch (R1/R3 -> null),
//    phase rotation (R4 -> null), occupancy 59-71% (R5 vs R0 -> null).
//    Sub-linear at 44% occupancy (1.38x, not 2x).
//  * 8 independent waves/SIMD x 24K cy issue each still leaves the pipe >50%
//    idle -> per-wave stalls cannot explain it after rotation.
// Remaining hypothesis: LOAD IMBALANCE + RAGGED DRAIN. Block work (sum of
// trips over 12 pairs) varies ~1.5-1.8x with column radius (edge columns get
// wide u-windows). Grid = 4096 blocks over ~2048 resident slots = ~2
// quantized generations, and y-major blockIdx makes a CU's consecutive grabs
// spatially ADJACENT -> heavy edge blocks cluster on the same CUs -> long
// ragged tail; avg Occupancy/VALUBusy diluted by the drain. Explains the
// 1.38x at half occupancy (more generations self-balance better).
// R21 = EXACT R4 kernel + bijective odd-multiplier scramble of the block
// index (bid' = bid*1337 mod 4096, gcd=1): each CU's sequential grabs become
// spatially pseudo-random, per-slot sums concentrate, tail shrinks. Per-block
// output is bit-for-bit identical (same (xq,y) set, same code).

#define SETUP_ANGLE(S, AIDX, AB)                                                 \
    const float c##S = CSA[AIDX], sn##S = SNA[AIDX];                             \
    const float c512##S = 512.0f * c##S;                                         \
    const float s512##S = 512.0f * sn##S;                                        \
    const float rho##S = fmaf(x0, c##S, fmaf(y0, sn##S, 256.0f));                \
    const float Vx##S = x0 + 256.0f * c##S;                                      \
    const float Vy##S = y0 + 256.0f * sn##S;                                     \
    const float tvlo##S = (rho##S - (AB)) * (1.0f / 512.0f);                     \
    const float yp##S = y0 * c##S - x0 * sn##S;                                  \
    const float rl##S = __builtin_amdgcn_rcpf(rho##S - (AB));                    \
    const float rh##S = __builtin_amdgcn_rcpf(rho##S + (AB));                    \
    const float A##S = yp##S - (AB), B##S = yp##S + (AB);                        \
    const float um##S = 512.0f * A##S * ((A##S >= 0.0f) ? rh##S : rl##S);        \
    const float uM##S = 512.0f * B##S * ((B##S >= 0.0f) ? rl##S : rh##S);        \
    const int u_lo##S = max(0,   (int)ceilf(um##S + 63.49f));                    \
    const int u_hi##S = min(127, (int)floorf(uM##S + 63.51f));                   \
    const int len##S = max(0, u_hi##S - u_lo##S + 1);                            \
    const float Zmin##S = fmaf(vvf, (vvf >= 0.0f) ? (tvlo##S - 1.0e-3f)          \
                                                  : (tvlo##S + 7.2e-3f), 31.5f); \
    const float izbf##S = floorf(Zmin##S);                                       \
    const int   izb##S  = (int)izbf##S;                                          \
    const v2f b0##S = {izbf##S, izbf##S};                                        \
    const float tDL##S = tvlo##S * INV_DL;                                       \
    const v2f mVx##S = {-Vx##S, -Vx##S}, mVy##S = {-Vy##S, -Vy##S};

#define BP_BODY2(S, RV, UU) do {                                                 \
    const float pu = fmaf(-(UU), sn##S, c512##S);                                \
    const float qu = fmaf((UU), c##S, s512##S);                                  \
    const float arg  = fmaf((UU), (UU), s2);                                     \
    const float invn = __builtin_amdgcn_rsqf(arg);                               \
    const float nn   = arg * invn;                                               \
    const float i0f  = ceilf(fmaf(tDL##S, nn, cK));                              \
    const float ell0 = fmaf(i0f, F_DL, F_L0);                                    \
    v2f tp; tp.x = ell0 * invn; tp.y = fmaf(F_DL, invn, tp.x);                   \
    const v2f pu2 = {pu, pu}, qu2 = {qu, qu};                                    \
    v2f wx = __builtin_elementwise_max(                                          \
        one2 - __builtin_elementwise_abs(__builtin_elementwise_fma(tp, pu2, mVx##S)), zero2); \
    v2f wy = __builtin_elementwise_max(                                          \
        one2 - __builtin_elementwise_abs(__builtin_elementwise_fma(tp, qu2, mVy##S)), zero2); \
    v2f val = wx * wy * (v2f){(RV), (RV)};                                       \
    const v2f fz2 = __builtin_elementwise_fma(tp, vv2, h31);                     \
    const v2f g  = fz2 - b0##S;                                                  \
    const v2f h1 = g - one2;                                                     \
    AC0##S = __builtin_elementwise_fma(__builtin_elementwise_max(                \
             one2 - __builtin_elementwise_abs(g), zero2), val, AC0##S);          \
    AC1##S = __builtin_elementwise_fma(__builtin_elementwise_max(                \
             one2 - __builtin_elementwise_abs(h1), zero2), val, AC1##S);         \
    AC2##S = __builtin_elementwise_fma(__builtin_elementwise_max(h1, zero2), val, AC2##S); \
} while (0)

__global__ __launch_bounds__(256, 8) void bp_gather20(const float* __restrict__ resT,
                                                      float* __restrict__ out) {
    __shared__ float s_acc[4 * 64];       // per-wave z-accumulator columns

    const int tid  = threadIdx.x;
    const int lane = tid & 63;            // = v
    const int wv   = tid >> 6;            // wave 0..3

    // scrambled block order: bijective on 4096 (gcd(1337,4096)=1).
    // Consecutive hardware grabs land 57 apart in y, 10 apart in xq ->
    // per-CU workloads decorrelate from the radius-dependent trip counts.
    const int bid  = (blockIdx.x * 1337) & 4095;
    const int y    = bid & 127;           // y-major
    const int xq   = bid >> 7;            // 0..31
    const int xi   = xq * 4 + wv;         // 4 consecutive x per block

    const float x0 = (float)xi - 63.5f;
    const float y0 = (float)y  - 63.5f;
    const float vvf = (float)lane - 31.5f;
    const float s2  = fmaf(vvf, vvf, 262144.0f);   // vv^2 + 512^2
    const v2f vv2   = {vvf, vvf};
    const v2f one2  = {1.0f, 1.0f}, zero2 = {0.0f, 0.0f};
    const v2f h31   = {31.5f, 31.5f};
    const float cK  = -(F_L0 * INV_DL) - 1.0e-3f;

    s_acc[tid] = 0.0f;

    // per-wave rotated pair order (kept from R4: free)
    int pj = __builtin_amdgcn_readfirstlane(3 * (tid >> 6));

    for (int j = 0; j < NA / 2; ++j) {
        const int a0 = __builtin_amdgcn_readfirstlane(2 * pj);
        const int a1 = a0 + 1;
        const float ab1a = fabsf(CSA[a0]) + fabsf(SNA[a0]);
        const float ab1b = fabsf(CSA[a1]) + fabsf(SNA[a1]);

        SETUP_ANGLE(0, a0, ab1a);         // adjacent pair: lengths nearly equal
        SETUP_ANGLE(1, a1, ab1b);

        const int trips = (max(len0, len1) + 1) & ~1;   // round up to even
        pj = (pj + 1 == NA / 2) ? 0 : pj + 1;
        if (trips == 0) continue;
        const int us0 = max(0, min(u_lo0, 128 - trips));
        const int us1 = max(0, min(u_lo1, 128 - trips));

        v2f AC00 = zero2, AC10 = zero2, AC20 = zero2;
        v2f AC01 = zero2, AC11 = zero2, AC21 = zero2;

        const float* ru0 = resT + (a0 << 13) + (us0 << 6) + lane;
        const float* ru1 = resT + (a1 << 13) + (us1 << 6) + lane;
        float uu0 = (float)us0 - 63.5f;
        float uu1 = (float)us1 - 63.5f;

        // 2-column prefetch pipeline; over-reads (<=3 cols past) stay inside ws
        float Ar0 = ru0[0],  Ar1 = ru1[0];
        float Br0 = ru0[64], Br1 = ru1[64];
#pragma unroll 1
        for (int k = 0; k < trips; k += 2) {
            const float Cr0 = ru0[128];
            const float Cr1 = ru1[128];
            const float Dr0 = ru0[192];
            const float Dr1 = ru1[192];
            BP_BODY2(0, Ar0, uu0);
            BP_BODY2(1, Ar1, uu1);
            BP_BODY2(0, Br0, uu0 + 1.0f);
            BP_BODY2(1, Br1, uu1 + 1.0f);
            Ar0 = Cr0; Ar1 = Cr1; Br0 = Dr0; Br1 = Dr1;
            ru0 += 128; ru1 += 128;
            uu0 += 2.0f; uu1 += 2.0f;
        }

        float* accw = s_acc + (wv << 6);      // wave-private column
        atomicAdd(&accw[izb0],     AC00.x + AC00.y);
        atomicAdd(&accw[izb0 + 1], AC10.x + AC10.y);
        atomicAdd(&accw[izb0 + 2], AC20.x + AC20.y);
        atomicAdd(&accw[izb1],     AC01.x + AC01.y);
        atomicAdd(&accw[izb1 + 1], AC11.x + AC11.y);
        atomicAdd(&accw[izb1 + 2], AC21.x + AC21.y);
    }
    __syncthreads();

    // writeout: 4 consecutive x per 4 lanes -> 16B chunks
    const int z  = tid >> 2;
    const int w4 = tid & 3;
    out[(z << 14) + (y << 7) + xq * 4 + w4] = s_acc[(w4 << 6) + z] * F_STEP;
}

extern "C" void kernel_launch(void* const* d_in, const int* in_sizes, int n_in,
                              void* d_out, int out_size, void* d_ws, size_t ws_size,
                              hipStream_t stream) {
    const float* x = (const float*)d_in[0];   // [1,1,64,128,128]
    const float* p = (const float*)d_in[1];   // [1,1,24,64,128]
    float* out  = (float*)d_out;              // [1,1,64,128,128]
    float* resT = (float*)d_ws;               // transposed filtered residual, NRAYS floats
    float* part = resT + NRAYS;               // 4 FP segments, 4*NRAYS floats
    float* padv = part + NSEG * NRAYS;        // padded volume, PVN floats (~4.6 MB)

    pad_kernel<<<(PVN + 255) / 256, 256, 0, stream>>>(x, padv);
    dim3 fpg(NRAYS / 256, NSEG);
    fp_seg_kernel<<<fpg, 256, 0, stream>>>(padv, part);
    ramp_kernel<<<NA * NV, NU, 0, stream>>>(part, p, resT);
    bp_gather20<<<128 * 32, 256, 0, stream>>>(resT, out);
}

// Round 7
// 431.804 us; speedup vs baseline: 1.0358x; 1.0358x over previous
//
#include <hip/hip_runtime.h>
#include <math.h>

// ---- geometry constants (match reference) ----
#define NA   24
#define NU   128
#define NV   64
#define NW   128   // volume W (x)
#define NH   128   // volume H (y)
#define ND   64    // volume D (z)
#define NS   128   // samples per ray
#define F_STEP 1.5625f            // 2*HS/S = 200/128
#define F_DL  (200.0f / 127.0f)   // linspace(156,356,128) spacing
#define F_L0  156.0f
#define INV_DL (127.0f / 200.0f)

#define NRAYS (NA * NV * NU)      // 196608
#define VOX   (NW * NH * ND)      // 1048576
#define NSEG  4

// padded volume: planes {guard, padz(-1), z0..z63, padz(64), guard} x 130 x 130
#define PPX  130
#define PPY  130
#define PPZ  68
#define PPLANE (PPX * PPY)        // 16900
#define PVN  (PPZ * PPLANE)       // 1,149,200
#define CBASE (2 * PPLANE + PPX + 1)   // voxel(0,0,0) linear offset

typedef float v2f __attribute__((ext_vector_type(2)));

// cos/sin(k*15 deg)
__device__ __constant__ float CSA[NA] = {
    1.0f,  0.96592582628906829f,  0.86602540378443865f,  0.70710678118654752f,
    0.5f,  0.25881904510252076f,  0.0f,                 -0.25881904510252076f,
   -0.5f, -0.70710678118654752f, -0.86602540378443865f, -0.96592582628906829f,
   -1.0f, -0.96592582628906829f, -0.86602540378443865f, -0.70710678118654752f,
   -0.5f, -0.25881904510252076f,  0.0f,                  0.25881904510252076f,
    0.5f,  0.70710678118654752f,  0.86602540378443865f,  0.96592582628906829f
};
__device__ __constant__ float SNA[NA] = {
    0.0f,  0.25881904510252076f,  0.5f,                  0.70710678118654752f,
    0.86602540378443865f,  0.96592582628906829f,  1.0f,  0.96592582628906829f,
    0.86602540378443865f,  0.70710678118654752f,  0.5f,  0.25881904510252076f,
    0.0f, -0.25881904510252076f, -0.5f,                 -0.70710678118654752f,
   -0.86602540378443865f, -0.96592582628906829f, -1.0f, -0.96592582628906829f,
   -0.86602540378443865f, -0.70710678118654752f, -0.5f, -0.25881904510252076f
};

// ---------------- volume padding: zero borders, copy interior ----------------
__global__ __launch_bounds__(256) void pad_kernel(const float* __restrict__ vol,
                                                  float* __restrict__ padv) {
    int i = blockIdx.x * 256 + threadIdx.x;
    if (i >= PVN) return;
    int x = i % PPX;
    int t = i / PPX;
    int y = t % PPY;
    int z = t / PPY;
    float val = 0.0f;
    if (z >= 2 && z <= 65 && y >= 1 && y <= 128 && x >= 1 && x <= 128)
        val = vol[(((z - 2) << 7) + (y - 1) << 7) + (x - 1)];
    padv[i] = val;
}

// Per-ray geometry for FP.
__device__ __forceinline__ void ray_setup(int a, int v, int u,
                                          float& sx, float& sy,
                                          float& dx, float& dy, float& dz) {
    float ang = (float)((double)a * (15.0 * M_PI / 180.0));
    float c = cosf(ang), s = sinf(ang);
    float uu = (float)u - 63.5f;
    float vv = (float)v - 31.5f;
    float ux = 512.0f * c - uu * s;
    float uy = 512.0f * s + uu * c;
    float uz = vv;
    float invn = 1.0f / sqrtf(ux * ux + uy * uy + uz * uz);
    dx = ux * invn; dy = uy * invn; dz = uz * invn;
    sx = -256.0f * c; sy = -256.0f * s;
}

// ---------------- forward projection, 4 ell-segments, padded-volume gather ----------------
__global__ __launch_bounds__(256) void fp_seg_kernel(const float* __restrict__ padv,
                                                     float* __restrict__ part) {
    int r = blockIdx.x * blockDim.x + threadIdx.x;
    int seg = blockIdx.y;
    int u = r & (NU - 1);
    int v = (r >> 7) & (NV - 1);
    int a = r >> 13;

    float sx, sy, dx, dy, dz;
    ray_setup(a, v, u, sx, sy, dx, dy, dz);

    // exact-support window (voxel weights are zero outside +-64.5 / +-32.5)
    float rx = 1.0f / dx, ry = 1.0f / dy, rz = 1.0f / dz;
    float ex0 = (-64.51f - sx) * rx, ex1 = (64.51f - sx) * rx;
    float ey0 = (-64.51f - sy) * ry, ey1 = (64.51f - sy) * ry;
    float ez0 = (-32.51f) * rz,      ez1 = (32.51f) * rz;
    float llo = fmaxf(fmaxf(fminf(ex0, ex1), fminf(ey0, ey1)), fminf(ez0, ez1));
    float lhi = fminf(fminf(fmaxf(ex0, ex1), fmaxf(ey0, ey1)), fmaxf(ez0, ez1));
    int i_lo = max(seg * 32,      (int)ceilf((llo - F_L0) * INV_DL));
    int i_hi = min(seg * 32 + 31, (int)floorf((lhi - F_L0) * INV_DL));

    float acc = 0.0f;
    for (int i = i_lo; i <= i_hi; ++i) {
        float ell = fmaf((float)i, F_DL, F_L0);
        float cx = fmaf(ell, dx, sx) + 63.5f;   // voxel-index space
        float cy = fmaf(ell, dy, sy) + 63.5f;
        float cz = ell * dz + 31.5f;
        float fx = floorf(cx), fy = floorf(cy), fz = floorf(cz);
        int ix = (int)fx, iy = (int)fy, iz = (int)fz;
        float wx1 = cx - fx, wy1 = cy - fy, wz1 = cz - fz;
        int base = iz * PPLANE + iy * PPX + ix + CBASE;
        const float* q0 = padv + base;
        const float* q1 = q0 + PPLANE;
        float v000 = q0[0],   v001 = q0[1];
        float v010 = q0[PPX], v011 = q0[PPX + 1];
        float v100 = q1[0],   v101 = q1[1];
        float v110 = q1[PPX], v111 = q1[PPX + 1];
        float c00 = fmaf(wx1, v001 - v000, v000);
        float c01 = fmaf(wx1, v011 - v010, v010);
        float c10 = fmaf(wx1, v101 - v100, v100);
        float c11 = fmaf(wx1, v111 - v110, v110);
        float c0  = fmaf(wy1, c01 - c00, c00);
        float c1  = fmaf(wy1, c11 - c10, c10);
        acc += fmaf(wz1, c1 - c0, c0);
    }
    part[seg * NRAYS + r] = acc;
}

// ------- residual + cw + Ram-Lak; writes TRANSPOSED resT[a][u][v] -------
__global__ __launch_bounds__(NU) void ramp_kernel(const float* __restrict__ part,
                                                  const float* __restrict__ p,
                                                  float* __restrict__ resT) {
    __shared__ float row[NU];
    int rowid = blockIdx.x;          // a*NV + v
    int u = threadIdx.x;
    int e = rowid * NU + u;
    int a = rowid >> 6;
    int v = rowid & (NV - 1);
    float sino = (part[e] + part[NRAYS + e] + part[2 * NRAYS + e] + part[3 * NRAYS + e]) * F_STEP;
    double du = (double)u - 64.0;
    double dv = (double)v - 32.0;
    float cw = (float)(512.0 / sqrt(262144.0 + dv * dv + du * du));
    row[u] = (sino - p[e]) * cw;
    __syncthreads();
    float acc = 0.125f * row[u];
#pragma unroll
    for (int d = 1; d <= 63; d += 2) {
        float f = (float)(-0.5 / (M_PI * M_PI * (double)(d * d)));
        float lo = (u - d >= 0) ? row[u - d] : 0.0f;
        float hi = (u + d < NU) ? row[u + d] : 0.0f;
        acc += f * (lo + hi);
    }
    resT[(a << 13) + (u << 6) + v] = acc;   // [a][u][v]
}

// ---------------- back projection: R4 structure + reduced-op body ----------------
// R22. Ledger (R0-R6): setup-prefetch null, occupancy trades null/negative,
// phase rotation null, FULL memory-path replacement null (R5 LDS == R0 global,
// bit-identical 335us), block scramble slightly negative (L2 locality loss).
// VALUBusy x dur == 160us in EVERY run; per-wave VALU duty ~8-10% LINEAR in
// resident waves. Only surviving theory: the kernel is VALU-THROUGHPUT-BOUND
// and the 45% VALUBusy reading is a miscalibrated gfx94x-fallback metric
// (likely normalized vs 2.4GHz max clock while the chip sustains lower).
// Hence the lever is VALU WORK. R22 keeps R4's proven envelope (32 VGPR,
// (256,8), occupancy 71%, global 2-col prefetch) and cuts the body 48->38 ops:
//  (1) z-tent sum identity: on the ALREADY-load-bearing invariant g in
//      [0,1.25] (Zmin eps-margins guarantee g>=0; AC2 ramp already assumes
//      g<=1.25), w0+w1+w2 == 1 exactly. Track ACS += val (2 ops) instead of
//      computing w0 (6 ops); reconstruct AC0 = ACS - AC1 - AC2 per pair.
//  (2) fuse fz/g/h1: only t = g-1 is needed now:
//      t = fma(tp, vv, (30.5 - izbf)) -- 6 ops -> 2.
//  (3) w1 = 1-|t| needs NO clamp: t in [-1,0.25] => 1-|t| >= 0 always.
// Padding bodies (val==0) are safe: finite t, weights multiply val=0.
// Numerics: AC0 reconstruction differs by ~1e-6 rel (sum identity exact in
// reals); everything else <=1ulp.

#define SETUP_ANGLE(S, AIDX, AB)                                                 \
    const float c##S = CSA[AIDX], sn##S = SNA[AIDX];                             \
    const float c512##S = 512.0f * c##S;                                         \
    const float s512##S = 512.0f * sn##S;                                        \
    const float rho##S = fmaf(x0, c##S, fmaf(y0, sn##S, 256.0f));                \
    const float Vx##S = x0 + 256.0f * c##S;                                      \
    const float Vy##S = y0 + 256.0f * sn##S;                                     \
    const float tvlo##S = (rho##S - (AB)) * (1.0f / 512.0f);                     \
    const float yp##S = y0 * c##S - x0 * sn##S;                                  \
    const float rl##S = __builtin_amdgcn_rcpf(rho##S - (AB));                    \
    const float rh##S = __builtin_amdgcn_rcpf(rho##S + (AB));                    \
    const float A##S = yp##S - (AB), B##S = yp##S + (AB);                        \
    const float um##S = 512.0f * A##S * ((A##S >= 0.0f) ? rh##S : rl##S);        \
    const float uM##S = 512.0f * B##S * ((B##S >= 0.0f) ? rl##S : rh##S);        \
    const int u_lo##S = max(0,   (int)ceilf(um##S + 63.49f));                    \
    const int u_hi##S = min(127, (int)floorf(uM##S + 63.51f));                   \
    const int len##S = max(0, u_hi##S - u_lo##S + 1);                            \
    const float Zmin##S = fmaf(vvf, (vvf >= 0.0f) ? (tvlo##S - 1.0e-3f)          \
                                                  : (tvlo##S + 7.2e-3f), 31.5f); \
    const float izbf##S = floorf(Zmin##S);                                       \
    const int   izb##S  = (int)izbf##S;                                          \
    const float kzm1s##S = 30.5f - izbf##S;                                      \
    const v2f kzm1##S = {kzm1s##S, kzm1s##S};                                    \
    const float tDL##S = tvlo##S * INV_DL;                                       \
    const v2f mVx##S = {-Vx##S, -Vx##S}, mVy##S = {-Vy##S, -Vy##S};

#define BP_BODY2(S, RV, UU) do {                                                 \
    const float pu = fmaf(-(UU), sn##S, c512##S);                                \
    const float qu = fmaf((UU), c##S, s512##S);                                  \
    const float arg  = fmaf((UU), (UU), s2);                                     \
    const float invn = __builtin_amdgcn_rsqf(arg);                               \
    const float nn   = arg * invn;                                               \
    const float i0f  = ceilf(fmaf(tDL##S, nn, cK));                              \
    const float ell0 = fmaf(i0f, F_DL, F_L0);                                    \
    v2f tp; tp.x = ell0 * invn; tp.y = fmaf(F_DL, invn, tp.x);                   \
    const v2f pu2 = {pu, pu}, qu2 = {qu, qu};                                    \
    v2f wx = __builtin_elementwise_max(                                          \
        one2 - __builtin_elementwise_abs(__builtin_elementwise_fma(tp, pu2, mVx##S)), zero2); \
    v2f wy = __builtin_elementwise_max(                                          \
        one2 - __builtin_elementwise_abs(__builtin_elementwise_fma(tp, qu2, mVy##S)), zero2); \
    v2f val = wx * wy * (v2f){(RV), (RV)};                                       \
    const v2f t  = __builtin_elementwise_fma(tp, vv2, kzm1##S);                  \
    const v2f w1 = one2 - __builtin_elementwise_abs(t);   /* no clamp: |t|<=1 */ \
    const v2f w2 = __builtin_elementwise_max(t, zero2);                          \
    AC1##S = __builtin_elementwise_fma(w1, val, AC1##S);                         \
    AC2##S = __builtin_elementwise_fma(w2, val, AC2##S);                         \
    ACS##S = ACS##S + val;                                                       \
} while (0)

__global__ __launch_bounds__(256, 8) void bp_gather21(const float* __restrict__ resT,
                                                      float* __restrict__ out) {
    __shared__ float s_acc[4 * 64];       // per-wave z-accumulator columns

    const int tid  = threadIdx.x;
    const int lane = tid & 63;            // = v
    const int wv   = tid >> 6;            // wave 0..3
    const int y    = blockIdx.x & 127;    // y-major
    const int xq   = blockIdx.x >> 7;     // 0..31
    const int xi   = xq * 4 + wv;         // 4 consecutive x per block

    const float x0 = (float)xi - 63.5f;
    const float y0 = (float)y  - 63.5f;
    const float vvf = (float)lane - 31.5f;
    const float s2  = fmaf(vvf, vvf, 262144.0f);   // vv^2 + 512^2
    const v2f vv2   = {vvf, vvf};
    const v2f one2  = {1.0f, 1.0f}, zero2 = {0.0f, 0.0f};
    const float cK  = -(F_L0 * INV_DL) - 1.0e-3f;

    s_acc[tid] = 0.0f;

    // per-wave rotated pair order (kept from R4: free)
    int pj = __builtin_amdgcn_readfirstlane(3 * (tid >> 6));

    for (int j = 0; j < NA / 2; ++j) {
        const int a0 = __builtin_amdgcn_readfirstlane(2 * pj);
        const int a1 = a0 + 1;
        const float ab1a = fabsf(CSA[a0]) + fabsf(SNA[a0]);
        const float ab1b = fabsf(CSA[a1]) + fabsf(SNA[a1]);

        SETUP_ANGLE(0, a0, ab1a);         // adjacent pair: lengths nearly equal
        SETUP_ANGLE(1, a1, ab1b);

        const int trips = (max(len0, len1) + 1) & ~1;   // round up to even
        pj = (pj + 1 == NA / 2) ? 0 : pj + 1;
        if (trips == 0) continue;
        const int us0 = max(0, min(u_lo0, 128 - trips));
        const int us1 = max(0, min(u_lo1, 128 - trips));

        v2f ACS0 = zero2, AC10 = zero2, AC20 = zero2;
        v2f ACS1 = zero2, AC11 = zero2, AC21 = zero2;

        const float* ru0 = resT + (a0 << 13) + (us0 << 6) + lane;
        const float* ru1 = resT + (a1 << 13) + (us1 << 6) + lane;
        float uu0 = (float)us0 - 63.5f;
        float uu1 = (float)us1 - 63.5f;

        // 2-column prefetch pipeline; over-reads (<=3 cols past) stay inside ws
        float Ar0 = ru0[0],  Ar1 = ru1[0];
        float Br0 = ru0[64], Br1 = ru1[64];
#pragma unroll 1
        for (int k = 0; k < trips; k += 2) {
            const float Cr0 = ru0[128];
            const float Cr1 = ru1[128];
            const float Dr0 = ru0[192];
            const float Dr1 = ru1[192];
            BP_BODY2(0, Ar0, uu0);
            BP_BODY2(1, Ar1, uu1);
            BP_BODY2(0, Br0, uu0 + 1.0f);
            BP_BODY2(1, Br1, uu1 + 1.0f);
            Ar0 = Cr0; Ar1 = Cr1; Br0 = Dr0; Br1 = Dr1;
            ru0 += 128; ru1 += 128;
            uu0 += 2.0f; uu1 += 2.0f;
        }

        // AC0 reconstruction: w0+w1+w2 == 1 for g in [0,1.25] (exact in reals)
        const v2f r00 = ACS0 - AC10 - AC20;
        const v2f r01 = ACS1 - AC11 - AC21;

        float* accw = s_acc + (wv << 6);      // wave-private column
        atomicAdd(&accw[izb0],     r00.x + r00.y);
        atomicAdd(&accw[izb0 + 1], AC10.x + AC10.y);
        atomicAdd(&accw[izb0 + 2], AC20.x + AC20.y);
        atomicAdd(&accw[izb1],     r01.x + r01.y);
        atomicAdd(&accw[izb1 + 1], AC11.x + AC11.y);
        atomicAdd(&accw[izb1 + 2], AC21.x + AC21.y);
    }
    __syncthreads();

    // writeout: 4 consecutive x per 4 lanes -> 16B chunks
    const int z  = tid >> 2;
    const int w4 = tid & 3;
    out[(z << 14) + (y << 7) + xq * 4 + w4] = s_acc[(w4 << 6) + z] * F_STEP;
}

extern "C" void kernel_launch(void* const* d_in, const int* in_sizes, int n_in,
                              void* d_out, int out_size, void* d_ws, size_t ws_size,
                              hipStream_t stream) {
    const float* x = (const float*)d_in[0];   // [1,1,64,128,128]
    const float* p = (const float*)d_in[1];   // [1,1,24,64,128]
    float* out  = (float*)d_out;              // [1,1,64,128,128]
    float* resT = (float*)d_ws;               // transposed filtered residual, NRAYS floats
    float* part = resT + NRAYS;               // 4 FP segments, 4*NRAYS floats
    float* padv = part + NSEG * NRAYS;        // padded volume, PVN floats (~4.6 MB)

    pad_kernel<<<(PVN + 255) / 256, 256, 0, stream>>>(x, padv);
    dim3 fpg(NRAYS / 256, NSEG);
    fp_seg_kernel<<<fpg, 256, 0, stream>>>(padv, part);
    ramp_kernel<<<NA * NV, NU, 0, stream>>>(part, p, resT);
    bp_gather21<<<128 * 32, 256, 0, stream>>>(resT, out);
}

// Round 8
// 429.710 us; speedup vs baseline: 1.0409x; 1.0049x over previous
//
#include <hip/hip_runtime.h>
#include <math.h>

// ---- geometry constants (match reference) ----
#define NA   24
#define NU   128
#define NV   64
#define NW   128   // volume W (x)
#define NH   128   // volume H (y)
#define ND   64    // volume D (z)
#define NS   128   // samples per ray
#define F_STEP 1.5625f            // 2*HS/S = 200/128
#define F_DL  (200.0f / 127.0f)   // linspace(156,356,128) spacing
#define F_L0  156.0f
#define INV_DL (127.0f / 200.0f)

#define NRAYS (NA * NV * NU)      // 196608
#define VOX   (NW * NH * ND)      // 1048576
#define NSEG  4

// padded volume: planes {guard, padz(-1), z0..z63, padz(64), guard} x 130 x 130
#define PPX  130
#define PPY  130
#define PPZ  68
#define PPLANE (PPX * PPY)        // 16900
#define PVN  (PPZ * PPLANE)       // 1,149,200
#define CBASE (2 * PPLANE + PPX + 1)   // voxel(0,0,0) linear offset

typedef float v2f __attribute__((ext_vector_type(2)));
// 8-byte vector load with only 4-byte alignment guarantee (per-lane x-pair).
// clang emits load <2 x float>, align 4 -> global_load_dwordx2 under ROCm's
// unaligned-access mode; if the backend splits it, we get the old 2 dwords
// (correct either way).
typedef float f2v __attribute__((ext_vector_type(2)));
typedef f2v __attribute__((aligned(4))) f2u;

// cos/sin(k*15 deg)
__device__ __constant__ float CSA[NA] = {
    1.0f,  0.96592582628906829f,  0.86602540378443865f,  0.70710678118654752f,
    0.5f,  0.25881904510252076f,  0.0f,                 -0.25881904510252076f,
   -0.5f, -0.70710678118654752f, -0.86602540378443865f, -0.96592582628906829f,
   -1.0f, -0.96592582628906829f, -0.86602540378443865f, -0.70710678118654752f,
   -0.5f, -0.25881904510252076f,  0.0f,                  0.25881904510252076f,
    0.5f,  0.70710678118654752f,  0.86602540378443865f,  0.96592582628906829f
};
__device__ __constant__ float SNA[NA] = {
    0.0f,  0.25881904510252076f,  0.5f,                  0.70710678118654752f,
    0.86602540378443865f,  0.96592582628906829f,  1.0f,  0.96592582628906829f,
    0.86602540378443865f,  0.70710678118654752f,  0.5f,  0.25881904510252076f,
    0.0f, -0.25881904510252076f, -0.5f,                 -0.70710678118654752f,
   -0.86602540378443865f, -0.96592582628906829f, -1.0f, -0.96592582628906829f,
   -0.86602540378443865f, -0.70710678118654752f, -0.5f, -0.25881904510252076f
};

// ---------------- volume padding: zero borders, copy interior ----------------
__global__ __launch_bounds__(256) void pad_kernel(const float* __restrict__ vol,
                                                  float* __restrict__ padv) {
    int i = blockIdx.x * 256 + threadIdx.x;
    if (i >= PVN) return;
    int x = i % PPX;
    int t = i / PPX;
    int y = t % PPY;
    int z = t / PPY;
    float val = 0.0f;
    if (z >= 2 && z <= 65 && y >= 1 && y <= 128 && x >= 1 && x <= 128)
        val = vol[(((z - 2) << 7) + (y - 1) << 7) + (x - 1)];
    padv[i] = val;
}

// Per-ray geometry for FP.
__device__ __forceinline__ void ray_setup(int a, int v, int u,
                                          float& sx, float& sy,
                                          float& dx, float& dy, float& dz) {
    float ang = (float)((double)a * (15.0 * M_PI / 180.0));
    float c = cosf(ang), s = sinf(ang);
    float uu = (float)u - 63.5f;
    float vv = (float)v - 31.5f;
    float ux = 512.0f * c - uu * s;
    float uy = 512.0f * s + uu * c;
    float uz = vv;
    float invn = 1.0f / sqrtf(ux * ux + uy * uy + uz * uz);
    dx = ux * invn; dy = uy * invn; dz = uz * invn;
    sx = -256.0f * c; sy = -256.0f * s;
}

// ---------------- forward projection, 4 ell-segments, padded-volume gather ----------------
// R23: the trilinear gather's 8 scalar loads come in 4 x-contiguous pairs;
// load each pair as one 8B vector (f2u, align-4). Halves load-instruction
// count per sample (the fp kernel is load-issue-bound on divergent gathers:
// ~163M gather instrs/dispatch, padv is L1/L2-resident so BW is not the
// limit). Identical bits consumed -> identical numerics.
__global__ __launch_bounds__(256) void fp_seg_kernel(const float* __restrict__ padv,
                                                     float* __restrict__ part) {
    int r = blockIdx.x * blockDim.x + threadIdx.x;
    int seg = blockIdx.y;
    int u = r & (NU - 1);
    int v = (r >> 7) & (NV - 1);
    int a = r >> 13;

    float sx, sy, dx, dy, dz;
    ray_setup(a, v, u, sx, sy, dx, dy, dz);

    // exact-support window (voxel weights are zero outside +-64.5 / +-32.5)
    float rx = 1.0f / dx, ry = 1.0f / dy, rz = 1.0f / dz;
    float ex0 = (-64.51f - sx) * rx, ex1 = (64.51f - sx) * rx;
    float ey0 = (-64.51f - sy) * ry, ey1 = (64.51f - sy) * ry;
    float ez0 = (-32.51f) * rz,      ez1 = (32.51f) * rz;
    float llo = fmaxf(fmaxf(fminf(ex0, ex1), fminf(ey0, ey1)), fminf(ez0, ez1));
    float lhi = fminf(fminf(fmaxf(ex0, ex1), fmaxf(ey0, ey1)), fmaxf(ez0, ez1));
    int i_lo = max(seg * 32,      (int)ceilf((llo - F_L0) * INV_DL));
    int i_hi = min(seg * 32 + 31, (int)floorf((lhi - F_L0) * INV_DL));

    float acc = 0.0f;
    for (int i = i_lo; i <= i_hi; ++i) {
        float ell = fmaf((float)i, F_DL, F_L0);
        float cx = fmaf(ell, dx, sx) + 63.5f;   // voxel-index space
        float cy = fmaf(ell, dy, sy) + 63.5f;
        float cz = ell * dz + 31.5f;
        float fx = floorf(cx), fy = floorf(cy), fz = floorf(cz);
        int ix = (int)fx, iy = (int)fy, iz = (int)fz;
        float wx1 = cx - fx, wy1 = cy - fy, wz1 = cz - fz;
        int base = iz * PPLANE + iy * PPX + ix + CBASE;
        const float* q0 = padv + base;
        const float* q1 = q0 + PPLANE;
        const f2u p00 = *(const f2u*)q0;           // (v000, v001)
        const f2u p01 = *(const f2u*)(q0 + PPX);   // (v010, v011)
        const f2u p10 = *(const f2u*)q1;           // (v100, v101)
        const f2u p11 = *(const f2u*)(q1 + PPX);   // (v110, v111)
        float c00 = fmaf(wx1, p00.y - p00.x, p00.x);
        float c01 = fmaf(wx1, p01.y - p01.x, p01.x);
        float c10 = fmaf(wx1, p10.y - p10.x, p10.x);
        float c11 = fmaf(wx1, p11.y - p11.x, p11.x);
        float c0  = fmaf(wy1, c01 - c00, c00);
        float c1  = fmaf(wy1, c11 - c10, c10);
        acc += fmaf(wz1, c1 - c0, c0);
    }
    part[seg * NRAYS + r] = acc;
}

// ------- residual + cw + Ram-Lak; writes TRANSPOSED resT[a][u][v] -------
__global__ __launch_bounds__(NU) void ramp_kernel(const float* __restrict__ part,
                                                  const float* __restrict__ p,
                                                  float* __restrict__ resT) {
    __shared__ float row[NU];
    int rowid = blockIdx.x;          // a*NV + v
    int u = threadIdx.x;
    int e = rowid * NU + u;
    int a = rowid >> 6;
    int v = rowid & (NV - 1);
    float sino = (part[e] + part[NRAYS + e] + part[2 * NRAYS + e] + part[3 * NRAYS + e]) * F_STEP;
    double du = (double)u - 64.0;
    double dv = (double)v - 32.0;
    float cw = (float)(512.0 / sqrt(262144.0 + dv * dv + du * du));
    row[u] = (sino - p[e]) * cw;
    __syncthreads();
    float acc = 0.125f * row[u];
#pragma unroll
    for (int d = 1; d <= 63; d += 2) {
        float f = (float)(-0.5 / (M_PI * M_PI * (double)(d * d)));
        float lo = (u - d >= 0) ? row[u - d] : 0.0f;
        float hi = (u + d < NU) ? row[u + d] : 0.0f;
        acc += f * (lo + hi);
    }
    resT[(a << 13) + (u << 6) + v] = acc;   // [a][u][v]
}

// ---------------- back projection: R7 kernel (kept: best @330us) ----------------
// Ledger (R0-R7): setup-prefetch null, occupancy trades null/negative, phase
// rotation null, full memory-path replacement null, block scramble negative,
// -21% VALU ops -> -1.5% wall (VALU-throughput refuted; VALUBusy 45->38.7%).
// bp sits at a ~330us multi-factor equilibrium; no measured resource >45%.
// Frozen this round; remaining session effort goes to fp_seg (~80us).

#define SETUP_ANGLE(S, AIDX, AB)                                                 \
    const float c##S = CSA[AIDX], sn##S = SNA[AIDX];                             \
    const float c512##S = 512.0f * c##S;                                         \
    const float s512##S = 512.0f * sn##S;                                        \
    const float rho##S = fmaf(x0, c##S, fmaf(y0, sn##S, 256.0f));                \
    const float Vx##S = x0 + 256.0f * c##S;                                      \
    const float Vy##S = y0 + 256.0f * sn##S;                                     \
    const float tvlo##S = (rho##S - (AB)) * (1.0f / 512.0f);                     \
    const float yp##S = y0 * c##S - x0 * sn##S;                                  \
    const float rl##S = __builtin_amdgcn_rcpf(rho##S - (AB));                    \
    const float rh##S = __builtin_amdgcn_rcpf(rho##S + (AB));                    \
    const float A##S = yp##S - (AB), B##S = yp##S + (AB);                        \
    const float um##S = 512.0f * A##S * ((A##S >= 0.0f) ? rh##S : rl##S);        \
    const float uM##S = 512.0f * B##S * ((B##S >= 0.0f) ? rl##S : rh##S);        \
    const int u_lo##S = max(0,   (int)ceilf(um##S + 63.49f));                    \
    const int u_hi##S = min(127, (int)floorf(uM##S + 63.51f));                   \
    const int len##S = max(0, u_hi##S - u_lo##S + 1);                            \
    const float Zmin##S = fmaf(vvf, (vvf >= 0.0f) ? (tvlo##S - 1.0e-3f)          \
                                                  : (tvlo##S + 7.2e-3f), 31.5f); \
    const float izbf##S = floorf(Zmin##S);                                       \
    const int   izb##S  = (int)izbf##S;                                          \
    const float kzm1s##S = 30.5f - izbf##S;                                      \
    const v2f kzm1##S = {kzm1s##S, kzm1s##S};                                    \
    const float tDL##S = tvlo##S * INV_DL;                                       \
    const v2f mVx##S = {-Vx##S, -Vx##S}, mVy##S = {-Vy##S, -Vy##S};

#define BP_BODY2(S, RV, UU) do {                                                 \
    const float pu = fmaf(-(UU), sn##S, c512##S);                                \
    const float qu = fmaf((UU), c##S, s512##S);                                  \
    const float arg  = fmaf((UU), (UU), s2);                                     \
    const float invn = __builtin_amdgcn_rsqf(arg);                               \
    const float nn   = arg * invn;                                               \
    const float i0f  = ceilf(fmaf(tDL##S, nn, cK));                              \
    const float ell0 = fmaf(i0f, F_DL, F_L0);                                    \
    v2f tp; tp.x = ell0 * invn; tp.y = fmaf(F_DL, invn, tp.x);                   \
    const v2f pu2 = {pu, pu}, qu2 = {qu, qu};                                    \
    v2f wx = __builtin_elementwise_max(                                          \
        one2 - __builtin_elementwise_abs(__builtin_elementwise_fma(tp, pu2, mVx##S)), zero2); \
    v2f wy = __builtin_elementwise_max(                                          \
        one2 - __builtin_elementwise_abs(__builtin_elementwise_fma(tp, qu2, mVy##S)), zero2); \
    v2f val = wx * wy * (v2f){(RV), (RV)};                                       \
    const v2f t  = __builtin_elementwise_fma(tp, vv2, kzm1##S);                  \
    const v2f w1 = one2 - __builtin_elementwise_abs(t);   /* no clamp: |t|<=1 */ \
    const v2f w2 = __builtin_elementwise_max(t, zero2);                          \
    AC1##S = __builtin_elementwise_fma(w1, val, AC1##S);                         \
    AC2##S = __builtin_elementwise_fma(w2, val, AC2##S);                         \
    ACS##S = ACS##S + val;                                                       \
} while (0)

__global__ __launch_bounds__(256, 8) void bp_gather21(const float* __restrict__ resT,
                                                      float* __restrict__ out) {
    __shared__ float s_acc[4 * 64];       // per-wave z-accumulator columns

    const int tid  = threadIdx.x;
    const int lane = tid & 63;            // = v
    const int wv   = tid >> 6;            // wave 0..3
    const int y    = blockIdx.x & 127;    // y-major
    const int xq   = blockIdx.x >> 7;     // 0..31
    const int xi   = xq * 4 + wv;         // 4 consecutive x per block

    const float x0 = (float)xi - 63.5f;
    const float y0 = (float)y  - 63.5f;
    const float vvf = (float)lane - 31.5f;
    const float s2  = fmaf(vvf, vvf, 262144.0f);   // vv^2 + 512^2
    const v2f vv2   = {vvf, vvf};
    const v2f one2  = {1.0f, 1.0f}, zero2 = {0.0f, 0.0f};
    const float cK  = -(F_L0 * INV_DL) - 1.0e-3f;

    s_acc[tid] = 0.0f;

    // per-wave rotated pair order (kept from R4: free)
    int pj = __builtin_amdgcn_readfirstlane(3 * (tid >> 6));

    for (int j = 0; j < NA / 2; ++j) {
        const int a0 = __builtin_amdgcn_readfirstlane(2 * pj);
        const int a1 = a0 + 1;
        const float ab1a = fabsf(CSA[a0]) + fabsf(SNA[a0]);
        const float ab1b = fabsf(CSA[a1]) + fabsf(SNA[a1]);

        SETUP_ANGLE(0, a0, ab1a);         // adjacent pair: lengths nearly equal
        SETUP_ANGLE(1, a1, ab1b);

        const int trips = (max(len0, len1) + 1) & ~1;   // round up to even
        pj = (pj + 1 == NA / 2) ? 0 : pj + 1;
        if (trips == 0) continue;
        const int us0 = max(0, min(u_lo0, 128 - trips));
        const int us1 = max(0, min(u_lo1, 128 - trips));

        v2f ACS0 = zero2, AC10 = zero2, AC20 = zero2;
        v2f ACS1 = zero2, AC11 = zero2, AC21 = zero2;

        const float* ru0 = resT + (a0 << 13) + (us0 << 6) + lane;
        const float* ru1 = resT + (a1 << 13) + (us1 << 6) + lane;
        float uu0 = (float)us0 - 63.5f;
        float uu1 = (float)us1 - 63.5f;

        // 2-column prefetch pipeline; over-reads (<=3 cols past) stay inside ws
        float Ar0 = ru0[0],  Ar1 = ru1[0];
        float Br0 = ru0[64], Br1 = ru1[64];
#pragma unroll 1
        for (int k = 0; k < trips; k += 2) {
            const float Cr0 = ru0[128];
            const float Cr1 = ru1[128];
            const float Dr0 = ru0[192];
            const float Dr1 = ru1[192];
            BP_BODY2(0, Ar0, uu0);
            BP_BODY2(1, Ar1, uu1);
            BP_BODY2(0, Br0, uu0 + 1.0f);
            BP_BODY2(1, Br1, uu1 + 1.0f);
            Ar0 = Cr0; Ar1 = Cr1; Br0 = Dr0; Br1 = Dr1;
            ru0 += 128; ru1 += 128;
            uu0 += 2.0f; uu1 += 2.0f;
        }

        // AC0 reconstruction: w0+w1+w2 == 1 for g in [0,1.25] (exact in reals)
        const v2f r00 = ACS0 - AC10 - AC20;
        const v2f r01 = ACS1 - AC11 - AC21;

        float* accw = s_acc + (wv << 6);      // wave-private column
        atomicAdd(&accw[izb0],     r00.x + r00.y);
        atomicAdd(&accw[izb0 + 1], AC10.x + AC10.y);
        atomicAdd(&accw[izb0 + 2], AC20.x + AC20.y);
        atomicAdd(&accw[izb1],     r01.x + r01.y);
        atomicAdd(&accw[izb1 + 1], AC11.x + AC11.y);
        atomicAdd(&accw[izb1 + 2], AC21.x + AC21.y);
    }
    __syncthreads();

    // writeout: 4 consecutive x per 4 lanes -> 16B chunks
    const int z  = tid >> 2;
    const int w4 = tid & 3;
    out[(z << 14) + (y << 7) + xq * 4 + w4] = s_acc[(w4 << 6) + z] * F_STEP;
}

extern "C" void kernel_launch(void* const* d_in, const int* in_sizes, int n_in,
                              void* d_out, int out_size, void* d_ws, size_t ws_size,
                              hipStream_t stream) {
    const float* x = (const float*)d_in[0];   // [1,1,64,128,128]
    const float* p = (const float*)d_in[1];   // [1,1,24,64,128]
    float* out  = (float*)d_out;              // [1,1,64,128,128]
    float* resT = (float*)d_ws;               // transposed filtered residual, NRAYS floats
    float* part = resT + NRAYS;               // 4 FP segments, 4*NRAYS floats
    float* padv = part + NSEG * NRAYS;        // padded volume, PVN floats (~4.6 MB)

    pad_kernel<<<(PVN + 255) / 256, 256, 0, stream>>>(x, padv);
    dim3 fpg(NRAYS / 256, NSEG);
    fp_seg_kernel<<<fpg, 256, 0, stream>>>(padv, part);
    ramp_kernel<<<NA * NV, NU, 0, stream>>>(part, p, resT);
    bp_gather21<<<128 * 32, 256, 0, stream>>>(resT, out);
}

// Round 9
// 413.073 us; speedup vs baseline: 1.0828x; 1.0403x over previous
//
#include <hip/hip_runtime.h>
#include <math.h>

// ---- geometry constants (match reference) ----
#define NA   24
#define NU   128
#define NV   64
#define NW   128   // volume W (x)
#define NH   128   // volume H (y)
#define ND   64    // volume D (z)
#define NS   128   // samples per ray
#define F_STEP 1.5625f            // 2*HS/S = 200/128
#define F_DL  (200.0f / 127.0f)   // linspace(156,356,128) spacing
#define F_L0  156.0f
#define INV_DL (127.0f / 200.0f)

#define NRAYS (NA * NV * NU)      // 196608
#define VOX   (NW * NH * ND)      // 1048576
#define NSEG  4

// padded volume: planes {guard, padz(-1), z0..z63, padz(64), guard} x 130 x 130
#define PPX  130
#define PPY  130
#define PPZ  68
#define PPLANE (PPX * PPY)        // 16900
#define PVN  (PPZ * PPLANE)       // 1,149,200
#define CBASE (2 * PPLANE + PPX + 1)   // voxel(0,0,0) linear offset

typedef float v2f __attribute__((ext_vector_type(2)));
// 8-byte vector load with only 4-byte alignment guarantee (per-lane x-pair).
typedef float f2v __attribute__((ext_vector_type(2)));
typedef f2v __attribute__((aligned(4))) f2u;

// cos/sin(k*15 deg)
__device__ __constant__ float CSA[NA] = {
    1.0f,  0.96592582628906829f,  0.86602540378443865f,  0.70710678118654752f,
    0.5f,  0.25881904510252076f,  0.0f,                 -0.25881904510252076f,
   -0.5f, -0.70710678118654752f, -0.86602540378443865f, -0.96592582628906829f,
   -1.0f, -0.96592582628906829f, -0.86602540378443865f, -0.70710678118654752f,
   -0.5f, -0.25881904510252076f,  0.0f,                  0.25881904510252076f,
    0.5f,  0.70710678118654752f,  0.86602540378443865f,  0.96592582628906829f
};
__device__ __constant__ float SNA[NA] = {
    0.0f,  0.25881904510252076f,  0.5f,                  0.70710678118654752f,
    0.86602540378443865f,  0.96592582628906829f,  1.0f,  0.96592582628906829f,
    0.86602540378443865f,  0.70710678118654752f,  0.5f,  0.25881904510252076f,
    0.0f, -0.25881904510252076f, -0.5f,                 -0.70710678118654752f,
   -0.86602540378443865f, -0.96592582628906829f, -1.0f, -0.96592582628906829f,
   -0.86602540378443865f, -0.70710678118654752f, -0.5f, -0.25881904510252076f
};

// ---------------- volume padding + out zero-init ----------------
// R24: also zeroes `out` (bp now accumulates via global atomicAdd from two
// half-blocks per voxel column). Piggybacked here to avoid any memset API
// inside graph capture; stream order pad -> ... -> bp guarantees visibility.
__global__ __launch_bounds__(256) void pad_kernel(const float* __restrict__ vol,
                                                  float* __restrict__ padv,
                                                  float* __restrict__ outz) {
    int i = blockIdx.x * 256 + threadIdx.x;
    if (i >= PVN) return;
    if (i < VOX) outz[i] = 0.0f;
    int x = i % PPX;
    int t = i / PPX;
    int y = t % PPY;
    int z = t / PPY;
    float val = 0.0f;
    if (z >= 2 && z <= 65 && y >= 1 && y <= 128 && x >= 1 && x <= 128)
        val = vol[(((z - 2) << 7) + (y - 1) << 7) + (x - 1)];
    padv[i] = val;
}

// Per-ray geometry for FP.
__device__ __forceinline__ void ray_setup(int a, int v, int u,
                                          float& sx, float& sy,
                                          float& dx, float& dy, float& dz) {
    float ang = (float)((double)a * (15.0 * M_PI / 180.0));
    float c = cosf(ang), s = sinf(ang);
    float uu = (float)u - 63.5f;
    float vv = (float)v - 31.5f;
    float ux = 512.0f * c - uu * s;
    float uy = 512.0f * s + uu * c;
    float uz = vv;
    float invn = 1.0f / sqrtf(ux * ux + uy * uy + uz * uz);
    dx = ux * invn; dy = uy * invn; dz = uz * invn;
    sx = -256.0f * c; sy = -256.0f * s;
}

// ---------------- forward projection, 4 ell-segments, padded-volume gather ----------------
// R24: unroll 2 on the sample loop. R23 (pair loads) bought only ~2us ->
// fp is LATENCY-bound, not load-issue-bound; unrolling doubles the number of
// independent gathers in flight (MLP) so the ~200cy L1/L2 gather latency
// overlaps across two samples. Same arithmetic per sample.
__global__ __launch_bounds__(256) void fp_seg_kernel(const float* __restrict__ padv,
                                                     float* __restrict__ part) {
    int r = blockIdx.x * blockDim.x + threadIdx.x;
    int seg = blockIdx.y;
    int u = r & (NU - 1);
    int v = (r >> 7) & (NV - 1);
    int a = r >> 13;

    float sx, sy, dx, dy, dz;
    ray_setup(a, v, u, sx, sy, dx, dy, dz);

    // exact-support window (voxel weights are zero outside +-64.5 / +-32.5)
    float rx = 1.0f / dx, ry = 1.0f / dy, rz = 1.0f / dz;
    float ex0 = (-64.51f - sx) * rx, ex1 = (64.51f - sx) * rx;
    float ey0 = (-64.51f - sy) * ry, ey1 = (64.51f - sy) * ry;
    float ez0 = (-32.51f) * rz,      ez1 = (32.51f) * rz;
    float llo = fmaxf(fmaxf(fminf(ex0, ex1), fminf(ey0, ey1)), fminf(ez0, ez1));
    float lhi = fminf(fminf(fmaxf(ex0, ex1), fmaxf(ey0, ey1)), fmaxf(ez0, ez1));
    int i_lo = max(seg * 32,      (int)ceilf((llo - F_L0) * INV_DL));
    int i_hi = min(seg * 32 + 31, (int)floorf((lhi - F_L0) * INV_DL));

    float acc = 0.0f;
#pragma unroll 2
    for (int i = i_lo; i <= i_hi; ++i) {
        float ell = fmaf((float)i, F_DL, F_L0);
        float cx = fmaf(ell, dx, sx) + 63.5f;   // voxel-index space
        float cy = fmaf(ell, dy, sy) + 63.5f;
        float cz = ell * dz + 31.5f;
        float fx = floorf(cx), fy = floorf(cy), fz = floorf(cz);
        int ix = (int)fx, iy = (int)fy, iz = (int)fz;
        float wx1 = cx - fx, wy1 = cy - fy, wz1 = cz - fz;
        int base = iz * PPLANE + iy * PPX + ix + CBASE;
        const float* q0 = padv + base;
        const float* q1 = q0 + PPLANE;
        const f2u p00 = *(const f2u*)q0;           // (v000, v001)
        const f2u p01 = *(const f2u*)(q0 + PPX);   // (v010, v011)
        const f2u p10 = *(const f2u*)q1;           // (v100, v101)
        const f2u p11 = *(const f2u*)(q1 + PPX);   // (v110, v111)
        float c00 = fmaf(wx1, p00.y - p00.x, p00.x);
        float c01 = fmaf(wx1, p01.y - p01.x, p01.x);
        float c10 = fmaf(wx1, p10.y - p10.x, p10.x);
        float c11 = fmaf(wx1, p11.y - p11.x, p11.x);
        float c0  = fmaf(wy1, c01 - c00, c00);
        float c1  = fmaf(wy1, c11 - c10, c10);
        acc += fmaf(wz1, c1 - c0, c0);
    }
    part[seg * NRAYS + r] = acc;
}

// ------- residual + cw + Ram-Lak; writes TRANSPOSED resT[a][u][v] -------
__global__ __launch_bounds__(NU) void ramp_kernel(const float* __restrict__ part,
                                                  const float* __restrict__ p,
                                                  float* __restrict__ resT) {
    __shared__ float row[NU];
    int rowid = blockIdx.x;          // a*NV + v
    int u = threadIdx.x;
    int e = rowid * NU + u;
    int a = rowid >> 6;
    int v = rowid & (NV - 1);
    float sino = (part[e] + part[NRAYS + e] + part[2 * NRAYS + e] + part[3 * NRAYS + e]) * F_STEP;
    double du = (double)u - 64.0;
    double dv = (double)v - 32.0;
    float cw = (float)(512.0 / sqrt(262144.0 + dv * dv + du * du));
    row[u] = (sino - p[e]) * cw;
    __syncthreads();
    float acc = 0.125f * row[u];
#pragma unroll
    for (int d = 1; d <= 63; d += 2) {
        float f = (float)(-0.5 / (M_PI * M_PI * (double)(d * d)));
        float lo = (u - d >= 0) ? row[u - d] : 0.0f;
        float hi = (u + d < NU) ? row[u + d] : 0.0f;
        acc += f * (lo + hi);
    }
    resT[(a << 13) + (u << 6) + v] = acc;   // [a][u][v]
}

// ---------------- back projection: half-angle blocks, 4 generations ----------------
// R24. The one macroscopic structure consistent with ALL R0-R8 data (wave
// lifetime 118us = 3x the zero-overlap serial bound ~40us; latency ruled out
// by R5; occupancy stuck at 71%): grid = 4096 blocks over 2048 residency
// slots = EXACTLY 2 quantized generations with ragged inter-generation edges.
// R6's scramble test of this was confounded (it also destroyed L2 locality
// and slowed the kernel). R24 tests it cleanly: split each block's 12 angle-
// pairs into TWO blocks of 6 (half = bid&1; consecutive bids share (xq,y) ->
// locality preserved; total SETUP work exactly conserved) -> 8192 blocks =
// 4 generations, half the work quantum. Halves combine via global atomicAdd
// (2 contributions/voxel; out zeroed in pad_kernel). Rotation dropped (null).
// Body/envelope unchanged from R7 (32 VGPR, (256,8), 38-op body).

#define SETUP_ANGLE(S, AIDX, AB)                                                 \
    const float c##S = CSA[AIDX], sn##S = SNA[AIDX];                             \
    const float c512##S = 512.0f * c##S;                                         \
    const float s512##S = 512.0f * sn##S;                                        \
    const float rho##S = fmaf(x0, c##S, fmaf(y0, sn##S, 256.0f));                \
    const float Vx##S = x0 + 256.0f * c##S;                                      \
    const float Vy##S = y0 + 256.0f * sn##S;                                     \
    const float tvlo##S = (rho##S - (AB)) * (1.0f / 512.0f);                     \
    const float yp##S = y0 * c##S - x0 * sn##S;                                  \
    const float rl##S = __builtin_amdgcn_rcpf(rho##S - (AB));                    \
    const float rh##S = __builtin_amdgcn_rcpf(rho##S + (AB));                    \
    const float A##S = yp##S - (AB), B##S = yp##S + (AB);                        \
    const float um##S = 512.0f * A##S * ((A##S >= 0.0f) ? rh##S : rl##S);        \
    const float uM##S = 512.0f * B##S * ((B##S >= 0.0f) ? rl##S : rh##S);        \
    const int u_lo##S = max(0,   (int)ceilf(um##S + 63.49f));                    \
    const int u_hi##S = min(127, (int)floorf(uM##S + 63.51f));                   \
    const int len##S = max(0, u_hi##S - u_lo##S + 1);                            \
    const float Zmin##S = fmaf(vvf, (vvf >= 0.0f) ? (tvlo##S - 1.0e-3f)          \
                                                  : (tvlo##S + 7.2e-3f), 31.5f); \
    const float izbf##S = floorf(Zmin##S);                                       \
    const int   izb##S  = (int)izbf##S;                                          \
    const float kzm1s##S = 30.5f - izbf##S;                                      \
    const v2f kzm1##S = {kzm1s##S, kzm1s##S};                                    \
    const float tDL##S = tvlo##S * INV_DL;                                       \
    const v2f mVx##S = {-Vx##S, -Vx##S}, mVy##S = {-Vy##S, -Vy##S};

#define BP_BODY2(S, RV, UU) do {                                                 \
    const float pu = fmaf(-(UU), sn##S, c512##S);                                \
    const float qu = fmaf((UU), c##S, s512##S);                                  \
    const float arg  = fmaf((UU), (UU), s2);                                     \
    const float invn = __builtin_amdgcn_rsqf(arg);                               \
    const float nn   = arg * invn;                                               \
    const float i0f  = ceilf(fmaf(tDL##S, nn, cK));                              \
    const float ell0 = fmaf(i0f, F_DL, F_L0);                                    \
    v2f tp; tp.x = ell0 * invn; tp.y = fmaf(F_DL, invn, tp.x);                   \
    const v2f pu2 = {pu, pu}, qu2 = {qu, qu};                                    \
    v2f wx = __builtin_elementwise_max(                                          \
        one2 - __builtin_elementwise_abs(__builtin_elementwise_fma(tp, pu2, mVx##S)), zero2); \
    v2f wy = __builtin_elementwise_max(                                          \
        one2 - __builtin_elementwise_abs(__builtin_elementwise_fma(tp, qu2, mVy##S)), zero2); \
    v2f val = wx * wy * (v2f){(RV), (RV)};                                       \
    const v2f t  = __builtin_elementwise_fma(tp, vv2, kzm1##S);                  \
    const v2f w1 = one2 - __builtin_elementwise_abs(t);   /* no clamp: |t|<=1 */ \
    const v2f w2 = __builtin_elementwise_max(t, zero2);                          \
    AC1##S = __builtin_elementwise_fma(w1, val, AC1##S);                         \
    AC2##S = __builtin_elementwise_fma(w2, val, AC2##S);                         \
    ACS##S = ACS##S + val;                                                       \
} while (0)

__global__ __launch_bounds__(256, 8) void bp_gather22(const float* __restrict__ resT,
                                                      float* __restrict__ out) {
    __shared__ float s_acc[4 * 64];       // per-wave z-accumulator columns

    const int tid  = threadIdx.x;
    const int lane = tid & 63;            // = v
    const int wv   = tid >> 6;            // wave 0..3

    const int bid  = blockIdx.x;          // 0..8191
    const int half = bid & 1;             // angle-pairs [0..5] or [6..11]
    const int y    = (bid >> 1) & 127;    // consecutive bids share (xq,y)
    const int xq   = bid >> 8;            // 0..31
    const int xi   = xq * 4 + wv;         // 4 consecutive x per block

    const float x0 = (float)xi - 63.5f;
    const float y0 = (float)y  - 63.5f;
    const float vvf = (float)lane - 31.5f;
    const float s2  = fmaf(vvf, vvf, 262144.0f);   // vv^2 + 512^2
    const v2f vv2   = {vvf, vvf};
    const v2f one2  = {1.0f, 1.0f}, zero2 = {0.0f, 0.0f};
    const float cK  = -(F_L0 * INV_DL) - 1.0e-3f;

    s_acc[tid] = 0.0f;

    const int pbase = half * 6;
    for (int jj = 0; jj < 6; ++jj) {
        const int pj = pbase + jj;        // wave-uniform (blockIdx-derived)
        const int a0 = 2 * pj, a1 = a0 + 1;
        const float ab1a = fabsf(CSA[a0]) + fabsf(SNA[a0]);
        const float ab1b = fabsf(CSA[a1]) + fabsf(SNA[a1]);

        SETUP_ANGLE(0, a0, ab1a);         // adjacent pair: lengths nearly equal
        SETUP_ANGLE(1, a1, ab1b);

        const int trips = (max(len0, len1) + 1) & ~1;   // round up to even
        if (trips == 0) continue;
        const int us0 = max(0, min(u_lo0, 128 - trips));
        const int us1 = max(0, min(u_lo1, 128 - trips));

        v2f ACS0 = zero2, AC10 = zero2, AC20 = zero2;
        v2f ACS1 = zero2, AC11 = zero2, AC21 = zero2;

        const float* ru0 = resT + (a0 << 13) + (us0 << 6) + lane;
        const float* ru1 = resT + (a1 << 13) + (us1 << 6) + lane;
        float uu0 = (float)us0 - 63.5f;
        float uu1 = (float)us1 - 63.5f;

        // 2-column prefetch pipeline; over-reads (<=3 cols past) stay inside ws
        float Ar0 = ru0[0],  Ar1 = ru1[0];
        float Br0 = ru0[64], Br1 = ru1[64];
#pragma unroll 1
        for (int k = 0; k < trips; k += 2) {
            const float Cr0 = ru0[128];
            const float Cr1 = ru1[128];
            const float Dr0 = ru0[192];
            const float Dr1 = ru1[192];
            BP_BODY2(0, Ar0, uu0);
            BP_BODY2(1, Ar1, uu1);
            BP_BODY2(0, Br0, uu0 + 1.0f);
            BP_BODY2(1, Br1, uu1 + 1.0f);
            Ar0 = Cr0; Ar1 = Cr1; Br0 = Dr0; Br1 = Dr1;
            ru0 += 128; ru1 += 128;
            uu0 += 2.0f; uu1 += 2.0f;
        }

        // AC0 reconstruction: w0+w1+w2 == 1 for g in [0,1.25] (exact in reals)
        const v2f r00 = ACS0 - AC10 - AC20;
        const v2f r01 = ACS1 - AC11 - AC21;

        float* accw = s_acc + (wv << 6);      // wave-private column
        atomicAdd(&accw[izb0],     r00.x + r00.y);
        atomicAdd(&accw[izb0 + 1], AC10.x + AC10.y);
        atomicAdd(&accw[izb0 + 2], AC20.x + AC20.y);
        atomicAdd(&accw[izb1],     r01.x + r01.y);
        atomicAdd(&accw[izb1 + 1], AC11.x + AC11.y);
        atomicAdd(&accw[izb1 + 2], AC21.x + AC21.y);
    }
    __syncthreads();

    // writeout: accumulate into out (2 half-blocks per voxel column)
    const int z  = tid >> 2;
    const int w4 = tid & 3;
    atomicAdd(&out[(z << 14) + (y << 7) + xq * 4 + w4],
              s_acc[(w4 << 6) + z] * F_STEP);
}

extern "C" void kernel_launch(void* const* d_in, const int* in_sizes, int n_in,
                              void* d_out, int out_size, void* d_ws, size_t ws_size,
                              hipStream_t stream) {
    const float* x = (const float*)d_in[0];   // [1,1,64,128,128]
    const float* p = (const float*)d_in[1];   // [1,1,24,64,128]
    float* out  = (float*)d_out;              // [1,1,64,128,128]
    float* resT = (float*)d_ws;               // transposed filtered residual, NRAYS floats
    float* part = resT + NRAYS;               // 4 FP segments, 4*NRAYS floats
    float* padv = part + NSEG * NRAYS;        // padded volume, PVN floats (~4.6 MB)

    pad_kernel<<<(PVN + 255) / 256, 256, 0, stream>>>(x, padv, out);
    dim3 fpg(NRAYS / 256, NSEG);
    fp_seg_kernel<<<fpg, 256, 0, stream>>>(padv, part);
    ramp_kernel<<<NA * NV, NU, 0, stream>>>(part, p, resT);
    bp_gather22<<<128 * 32 * 2, 256, 0, stream>>>(resT, out);
}

// Round 10
// 409.863 us; speedup vs baseline: 1.0913x; 1.0078x over previous
//
#include <hip/hip_runtime.h>
#include <math.h>

// ---- geometry constants (match reference) ----
#define NA   24
#define NU   128
#define NV   64
#define NW   128   // volume W (x)
#define NH   128   // volume H (y)
#define ND   64    // volume D (z)
#define NS   128   // samples per ray
#define F_STEP 1.5625f            // 2*HS/S = 200/128
#define F_DL  (200.0f / 127.0f)   // linspace(156,356,128) spacing
#define F_L0  156.0f
#define INV_DL (127.0f / 200.0f)

#define NRAYS (NA * NV * NU)      // 196608
#define VOX   (NW * NH * ND)      // 1048576
#define NSEG  4

// padded volume: planes {guard, padz(-1), z0..z63, padz(64), guard} x 130 x 130
#define PPX  130
#define PPY  130
#define PPZ  68
#define PPLANE (PPX * PPY)        // 16900
#define PVN  (PPZ * PPLANE)       // 1,149,200
#define CBASE (2 * PPLANE + PPX + 1)   // voxel(0,0,0) linear offset

typedef float v2f __attribute__((ext_vector_type(2)));
// 8-byte vector load with only 4-byte alignment guarantee (per-lane x-pair).
typedef float f2v __attribute__((ext_vector_type(2)));
typedef f2v __attribute__((aligned(4))) f2u;

// cos/sin(k*15 deg)
__device__ __constant__ float CSA[NA] = {
    1.0f,  0.96592582628906829f,  0.86602540378443865f,  0.70710678118654752f,
    0.5f,  0.25881904510252076f,  0.0f,                 -0.25881904510252076f,
   -0.5f, -0.70710678118654752f, -0.86602540378443865f, -0.96592582628906829f,
   -1.0f, -0.96592582628906829f, -0.86602540378443865f, -0.70710678118654752f,
   -0.5f, -0.25881904510252076f,  0.0f,                  0.25881904510252076f,
    0.5f,  0.70710678118654752f,  0.86602540378443865f,  0.96592582628906829f
};
__device__ __constant__ float SNA[NA] = {
    0.0f,  0.25881904510252076f,  0.5f,                  0.70710678118654752f,
    0.86602540378443865f,  0.96592582628906829f,  1.0f,  0.96592582628906829f,
    0.86602540378443865f,  0.70710678118654752f,  0.5f,  0.25881904510252076f,
    0.0f, -0.25881904510252076f, -0.5f,                 -0.70710678118654752f,
   -0.86602540378443865f, -0.96592582628906829f, -1.0f, -0.96592582628906829f,
   -0.86602540378443865f, -0.70710678118654752f, -0.5f, -0.25881904510252076f
};

// ---------------- volume padding + out zero-init ----------------
// Zeroes `out` (bp accumulates via global atomicAdd from four quarter-blocks
// per voxel column). Piggybacked here: no memset API inside graph capture;
// stream order pad -> ... -> bp guarantees visibility.
__global__ __launch_bounds__(256) void pad_kernel(const float* __restrict__ vol,
                                                  float* __restrict__ padv,
                                                  float* __restrict__ outz) {
    int i = blockIdx.x * 256 + threadIdx.x;
    if (i >= PVN) return;
    if (i < VOX) outz[i] = 0.0f;
    int x = i % PPX;
    int t = i / PPX;
    int y = t % PPY;
    int z = t / PPY;
    float val = 0.0f;
    if (z >= 2 && z <= 65 && y >= 1 && y <= 128 && x >= 1 && x <= 128)
        val = vol[(((z - 2) << 7) + (y - 1) << 7) + (x - 1)];
    padv[i] = val;
}

// Per-ray geometry for FP.
__device__ __forceinline__ void ray_setup(int a, int v, int u,
                                          float& sx, float& sy,
                                          float& dx, float& dy, float& dz) {
    float ang = (float)((double)a * (15.0 * M_PI / 180.0));
    float c = cosf(ang), s = sinf(ang);
    float uu = (float)u - 63.5f;
    float vv = (float)v - 31.5f;
    float ux = 512.0f * c - uu * s;
    float uy = 512.0f * s + uu * c;
    float uz = vv;
    float invn = 1.0f / sqrtf(ux * ux + uy * uy + uz * uz);
    dx = ux * invn; dy = uy * invn; dz = uz * invn;
    sx = -256.0f * c; sy = -256.0f * s;
}

// ---------------- forward projection, 4 ell-segments, padded-volume gather ----------------
// R25: reverted R24's unroll-2 (non-bp time went 97 -> 106us: the extra
// in-flight state hurt more than the MLP helped). Back to R23 form.
__global__ __launch_bounds__(256) void fp_seg_kernel(const float* __restrict__ padv,
                                                     float* __restrict__ part) {
    int r = blockIdx.x * blockDim.x + threadIdx.x;
    int seg = blockIdx.y;
    int u = r & (NU - 1);
    int v = (r >> 7) & (NV - 1);
    int a = r >> 13;

    float sx, sy, dx, dy, dz;
    ray_setup(a, v, u, sx, sy, dx, dy, dz);

    // exact-support window (voxel weights are zero outside +-64.5 / +-32.5)
    float rx = 1.0f / dx, ry = 1.0f / dy, rz = 1.0f / dz;
    float ex0 = (-64.51f - sx) * rx, ex1 = (64.51f - sx) * rx;
    float ey0 = (-64.51f - sy) * ry, ey1 = (64.51f - sy) * ry;
    float ez0 = (-32.51f) * rz,      ez1 = (32.51f) * rz;
    float llo = fmaxf(fmaxf(fminf(ex0, ex1), fminf(ey0, ey1)), fminf(ez0, ez1));
    float lhi = fminf(fminf(fmaxf(ex0, ex1), fmaxf(ey0, ey1)), fmaxf(ez0, ez1));
    int i_lo = max(seg * 32,      (int)ceilf((llo - F_L0) * INV_DL));
    int i_hi = min(seg * 32 + 31, (int)floorf((lhi - F_L0) * INV_DL));

    float acc = 0.0f;
    for (int i = i_lo; i <= i_hi; ++i) {
        float ell = fmaf((float)i, F_DL, F_L0);
        float cx = fmaf(ell, dx, sx) + 63.5f;   // voxel-index space
        float cy = fmaf(ell, dy, sy) + 63.5f;
        float cz = ell * dz + 31.5f;
        float fx = floorf(cx), fy = floorf(cy), fz = floorf(cz);
        int ix = (int)fx, iy = (int)fy, iz = (int)fz;
        float wx1 = cx - fx, wy1 = cy - fy, wz1 = cz - fz;
        int base = iz * PPLANE + iy * PPX + ix + CBASE;
        const float* q0 = padv + base;
        const float* q1 = q0 + PPLANE;
        const f2u p00 = *(const f2u*)q0;           // (v000, v001)
        const f2u p01 = *(const f2u*)(q0 + PPX);   // (v010, v011)
        const f2u p10 = *(const f2u*)q1;           // (v100, v101)
        const f2u p11 = *(const f2u*)(q1 + PPX);   // (v110, v111)
        float c00 = fmaf(wx1, p00.y - p00.x, p00.x);
        float c01 = fmaf(wx1, p01.y - p01.x, p01.x);
        float c10 = fmaf(wx1, p10.y - p10.x, p10.x);
        float c11 = fmaf(wx1, p11.y - p11.x, p11.x);
        float c0  = fmaf(wy1, c01 - c00, c00);
        float c1  = fmaf(wy1, c11 - c10, c10);
        acc += fmaf(wz1, c1 - c0, c0);
    }
    part[seg * NRAYS + r] = acc;
}

// ------- residual + cw + Ram-Lak; writes TRANSPOSED resT[a][u][v] -------
__global__ __launch_bounds__(NU) void ramp_kernel(const float* __restrict__ part,
                                                  const float* __restrict__ p,
                                                  float* __restrict__ resT) {
    __shared__ float row[NU];
    int rowid = blockIdx.x;          // a*NV + v
    int u = threadIdx.x;
    int e = rowid * NU + u;
    int a = rowid >> 6;
    int v = rowid & (NV - 1);
    float sino = (part[e] + part[NRAYS + e] + part[2 * NRAYS + e] + part[3 * NRAYS + e]) * F_STEP;
    double du = (double)u - 64.0;
    double dv = (double)v - 32.0;
    float cw = (float)(512.0 / sqrt(262144.0 + dv * dv + du * du));
    row[u] = (sino - p[e]) * cw;
    __syncthreads();
    float acc = 0.125f * row[u];
#pragma unroll
    for (int d = 1; d <= 63; d += 2) {
        float f = (float)(-0.5 / (M_PI * M_PI * (double)(d * d)));
        float lo = (u - d >= 0) ? row[u - d] : 0.0f;
        float hi = (u + d < NU) ? row[u + d] : 0.0f;
        acc += f * (lo + hi);
    }
    resT[(a << 13) + (u << 6) + v] = acc;   // [a][u][v]
}

// ---------------- back projection: quarter-angle blocks, 8 generations ----------------
// R25. R24 CONFIRMED generation-quantization: halving the block work quantum
// (12->6 pairs, 2->4 generations) cut bp 333->307us, occupancy 71->83.6%.
// Mechanism: wall = conserved wave-time / concurrency; smaller quanta pack
// tighter and shrink the ragged drain. R25 halves again: 3 pairs/block,
// 16384 blocks = 8 generations (quarter = bid&3; consecutive bids share
// (xq,y) -> locality preserved; SETUP work exactly conserved). Four atomic
// contributions per voxel (out zeroed in pad). If this lands >=303us the
// direction is exhausted (asymptote ~ per-wave duty floor) -> declare plateau.
// Body/envelope unchanged from R7 (32 VGPR, (256,8), 38-op body).

#define SETUP_ANGLE(S, AIDX, AB)                                                 \
    const float c##S = CSA[AIDX], sn##S = SNA[AIDX];                             \
    const float c512##S = 512.0f * c##S;                                         \
    const float s512##S = 512.0f * sn##S;                                        \
    const float rho##S = fmaf(x0, c##S, fmaf(y0, sn##S, 256.0f));                \
    const float Vx##S = x0 + 256.0f * c##S;                                      \
    const float Vy##S = y0 + 256.0f * sn##S;                                     \
    const float tvlo##S = (rho##S - (AB)) * (1.0f / 512.0f);                     \
    const float yp##S = y0 * c##S - x0 * sn##S;                                  \
    const float rl##S = __builtin_amdgcn_rcpf(rho##S - (AB));                    \
    const float rh##S = __builtin_amdgcn_rcpf(rho##S + (AB));                    \
    const float A##S = yp##S - (AB), B##S = yp##S + (AB);                        \
    const float um##S = 512.0f * A##S * ((A##S >= 0.0f) ? rh##S : rl##S);        \
    const float uM##S = 512.0f * B##S * ((B##S >= 0.0f) ? rl##S : rh##S);        \
    const int u_lo##S = max(0,   (int)ceilf(um##S + 63.49f));                    \
    const int u_hi##S = min(127, (int)floorf(uM##S + 63.51f));                   \
    const int len##S = max(0, u_hi##S - u_lo##S + 1);                            \
    const float Zmin##S = fmaf(vvf, (vvf >= 0.0f) ? (tvlo##S - 1.0e-3f)          \
                                                  : (tvlo##S + 7.2e-3f), 31.5f); \
    const float izbf##S = floorf(Zmin##S);                                       \
    const int   izb##S  = (int)izbf##S;                                          \
    const float kzm1s##S = 30.5f - izbf##S;                                      \
    const v2f kzm1##S = {kzm1s##S, kzm1s##S};                                    \
    const float tDL##S = tvlo##S * INV_DL;                                       \
    const v2f mVx##S = {-Vx##S, -Vx##S}, mVy##S = {-Vy##S, -Vy##S};

#define BP_BODY2(S, RV, UU) do {                                                 \
    const float pu = fmaf(-(UU), sn##S, c512##S);                                \
    const float qu = fmaf((UU), c##S, s512##S);                                  \
    const float arg  = fmaf((UU), (UU), s2);                                     \
    const float invn = __builtin_amdgcn_rsqf(arg);                               \
    const float nn   = arg * invn;                                               \
    const float i0f  = ceilf(fmaf(tDL##S, nn, cK));                              \
    const float ell0 = fmaf(i0f, F_DL, F_L0);                                    \
    v2f tp; tp.x = ell0 * invn; tp.y = fmaf(F_DL, invn, tp.x);                   \
    const v2f pu2 = {pu, pu}, qu2 = {qu, qu};                                    \
    v2f wx = __builtin_elementwise_max(                                          \
        one2 - __builtin_elementwise_abs(__builtin_elementwise_fma(tp, pu2, mVx##S)), zero2); \
    v2f wy = __builtin_elementwise_max(                                          \
        one2 - __builtin_elementwise_abs(__builtin_elementwise_fma(tp, qu2, mVy##S)), zero2); \
    v2f val = wx * wy * (v2f){(RV), (RV)};                                       \
    const v2f t  = __builtin_elementwise_fma(tp, vv2, kzm1##S);                  \
    const v2f w1 = one2 - __builtin_elementwise_abs(t);   /* no clamp: |t|<=1 */ \
    const v2f w2 = __builtin_elementwise_max(t, zero2);                          \
    AC1##S = __builtin_elementwise_fma(w1, val, AC1##S);                         \
    AC2##S = __builtin_elementwise_fma(w2, val, AC2##S);                         \
    ACS##S = ACS##S + val;                                                       \
} while (0)

__global__ __launch_bounds__(256, 8) void bp_gather23(const float* __restrict__ resT,
                                                      float* __restrict__ out) {
    __shared__ float s_acc[4 * 64];       // per-wave z-accumulator columns

    const int tid  = threadIdx.x;
    const int lane = tid & 63;            // = v
    const int wv   = tid >> 6;            // wave 0..3

    const int bid  = blockIdx.x;          // 0..16383
    const int quarter = bid & 3;          // angle-pairs [3q .. 3q+2]
    const int y    = (bid >> 2) & 127;    // consecutive bids share (xq,y)
    const int xq   = bid >> 9;            // 0..31
    const int xi   = xq * 4 + wv;         // 4 consecutive x per block

    const float x0 = (float)xi - 63.5f;
    const float y0 = (float)y  - 63.5f;
    const float vvf = (float)lane - 31.5f;
    const float s2  = fmaf(vvf, vvf, 262144.0f);   // vv^2 + 512^2
    const v2f vv2   = {vvf, vvf};
    const v2f one2  = {1.0f, 1.0f}, zero2 = {0.0f, 0.0f};
    const float cK  = -(F_L0 * INV_DL) - 1.0e-3f;

    s_acc[tid] = 0.0f;

    const int pbase = quarter * 3;
    for (int jj = 0; jj < 3; ++jj) {
        const int pj = pbase + jj;        // wave-uniform (blockIdx-derived)
        const int a0 = 2 * pj, a1 = a0 + 1;
        const float ab1a = fabsf(CSA[a0]) + fabsf(SNA[a0]);
        const float ab1b = fabsf(CSA[a1]) + fabsf(SNA[a1]);

        SETUP_ANGLE(0, a0, ab1a);         // adjacent pair: lengths nearly equal
        SETUP_ANGLE(1, a1, ab1b);

        const int trips = (max(len0, len1) + 1) & ~1;   // round up to even
        if (trips == 0) continue;
        const int us0 = max(0, min(u_lo0, 128 - trips));
        const int us1 = max(0, min(u_lo1, 128 - trips));

        v2f ACS0 = zero2, AC10 = zero2, AC20 = zero2;
        v2f ACS1 = zero2, AC11 = zero2, AC21 = zero2;

        const float* ru0 = resT + (a0 << 13) + (us0 << 6) + lane;
        const float* ru1 = resT + (a1 << 13) + (us1 << 6) + lane;
        float uu0 = (float)us0 - 63.5f;
        float uu1 = (float)us1 - 63.5f;

        // 2-column prefetch pipeline; over-reads (<=3 cols past) stay inside ws
        float Ar0 = ru0[0],  Ar1 = ru1[0];
        float Br0 = ru0[64], Br1 = ru1[64];
#pragma unroll 1
        for (int k = 0; k < trips; k += 2) {
            const float Cr0 = ru0[128];
            const float Cr1 = ru1[128];
            const float Dr0 = ru0[192];
            const float Dr1 = ru1[192];
            BP_BODY2(0, Ar0, uu0);
            BP_BODY2(1, Ar1, uu1);
            BP_BODY2(0, Br0, uu0 + 1.0f);
            BP_BODY2(1, Br1, uu1 + 1.0f);
            Ar0 = Cr0; Ar1 = Cr1; Br0 = Dr0; Br1 = Dr1;
            ru0 += 128; ru1 += 128;
            uu0 += 2.0f; uu1 += 2.0f;
        }

        // AC0 reconstruction: w0+w1+w2 == 1 for g in [0,1.25] (exact in reals)
        const v2f r00 = ACS0 - AC10 - AC20;
        const v2f r01 = ACS1 - AC11 - AC21;

        float* accw = s_acc + (wv << 6);      // wave-private column
        atomicAdd(&accw[izb0],     r00.x + r00.y);
        atomicAdd(&accw[izb0 + 1], AC10.x + AC10.y);
        atomicAdd(&accw[izb0 + 2], AC20.x + AC20.y);
        atomicAdd(&accw[izb1],     r01.x + r01.y);
        atomicAdd(&accw[izb1 + 1], AC11.x + AC11.y);
        atomicAdd(&accw[izb1 + 2], AC21.x + AC21.y);
    }
    __syncthreads();

    // writeout: accumulate into out (4 quarter-blocks per voxel column)
    const int z  = tid >> 2;
    const int w4 = tid & 3;
    atomicAdd(&out[(z << 14) + (y << 7) + xq * 4 + w4],
              s_acc[(w4 << 6) + z] * F_STEP);
}

extern "C" void kernel_launch(void* const* d_in, const int* in_sizes, int n_in,
                              void* d_out, int out_size, void* d_ws, size_t ws_size,
                              hipStream_t stream) {
    const float* x = (const float*)d_in[0];   // [1,1,64,128,128]
    const float* p = (const float*)d_in[1];   // [1,1,24,64,128]
    float* out  = (float*)d_out;              // [1,1,64,128,128]
    float* resT = (float*)d_ws;               // transposed filtered residual, NRAYS floats
    float* part = resT + NRAYS;               // 4 FP segments, 4*NRAYS floats
    float* padv = part + NSEG * NRAYS;        // padded volume, PVN floats (~4.6 MB)

    pad_kernel<<<(PVN + 255) / 256, 256, 0, stream>>>(x, padv, out);
    dim3 fpg(NRAYS / 256, NSEG);
    fp_seg_kernel<<<fpg, 256, 0, stream>>>(padv, part);
    ramp_kernel<<<NA * NV, NU, 0, stream>>>(part, p, resT);
    bp_gather23<<<128 * 32 * 4, 256, 0, stream>>>(resT, out);
}